// Round 15
// baseline (398.211 us; speedup 1.0000x reference)
//
#include <hip/hip_runtime.h>
#include <hip/hip_bf16.h>
#include <hip/hip_fp16.h>
#include <math.h>

#define N_ATOMS 5000
#define N_EDGES 100000
#define F 128
#define B 20
#define NL 3
#define CAP 64

constexpr float CUTOFF = 5.0f;
constexpr float PI_F = 3.14159265358979323846f;

typedef _Float16 f16x8 __attribute__((ext_vector_type(8)));
typedef _Float16 h2 __attribute__((ext_vector_type(2)));
typedef float f32x4 __attribute__((ext_vector_type(4)));

struct EMeta { int src; float env; float u0, u1, u2; int pad[3]; };  // 32 B
struct __align__(4) U3 { unsigned int x, y, z; };                    // 12 B pv record

__device__ __forceinline__ float silu_f(float x) { return x / (1.0f + __expf(-x)); }

// pv layout: per (atom, t): [phi0, phi1, phi2, v0, v1, v2] f16 (12 B)
#define PV_IDX(atom, t) (((size_t)(atom) * F + (t)) * 6)

// ---------------------------------------------------------------- init
__global__ void init_kernel(const int* __restrict__ Z, const float* __restrict__ emb,
                            float* __restrict__ s, _Float16* __restrict__ s_h,
                            float* __restrict__ v, _Float16* __restrict__ pv,
                            int* __restrict__ count) {
    int atom = blockIdx.x;
    int t = threadIdx.x;
    float val = emb[Z[atom] * F + t];
    s[atom * F + t] = val;
    s_h[atom * F + t] = (_Float16)val;
#pragma unroll
    for (int d = 0; d < 3; ++d) v[(size_t)atom * 3 * F + d * F + t] = 0.0f;
    unsigned int* pp = (unsigned int*)(pv + PV_IDX(atom, t));
    pp[0] = 0u; pp[1] = 0u; pp[2] = 0u;
    if (t == 0) count[atom] = 0;
}

// ---------------------------------------------------------------- bucket edges by dst
__global__ void fill_buckets(const int* __restrict__ eidx, int* __restrict__ count,
                             int* __restrict__ bucket) {
    int e = blockIdx.x * 256 + threadIdx.x;
    if (e >= N_EDGES) return;
    int dst = eidx[2 * e];
    int pos = atomicAdd(&count[dst], 1);
    if (pos < CAP) bucket[dst * CAP + pos] = e;
}

// ---------------------------------------------------------------- per-slot edge metadata
__global__ void edge_meta_kernel(const int* __restrict__ count, const int* __restrict__ bucket,
                                 const int* __restrict__ eidx, const float* __restrict__ ediff,
                                 const float* __restrict__ edist,
                                 EMeta* __restrict__ meta, _Float16* __restrict__ rbfh) {
    int slot = blockIdx.x * 256 + threadIdx.x;
    if (slot >= N_ATOMS * CAP) return;
    int a = slot / CAP, i = slot % CAP;
    if (i >= count[a]) return;
    int e = bucket[slot];
    float d = edist[e];
    EMeta m;
    m.src = eidx[2 * e + 1];
    float fc = 0.5f * (cosf(PI_F * d / CUTOFF) + 1.0f);
    m.env = (d < CUTOFF) ? fc : 0.0f;
    float inv = 1.0f / d;
    m.u0 = ediff[3 * e + 0] * inv;
    m.u1 = ediff[3 * e + 1] * inv;
    m.u2 = ediff[3 * e + 2] * inv;
    m.pad[0] = m.pad[1] = m.pad[2] = 0;
    meta[slot] = m;
    _Float16* rp = rbfh + (size_t)slot * 24;
#pragma unroll
    for (int b = 0; b < B; ++b)
        rp[b] = (_Float16)(sinf(d * (float)(b + 1) * (PI_F / CUTOFF)) / d);
    rp[20] = rp[21] = rp[22] = rp[23] = (_Float16)0.0f;
}

// ---------------------------------------------------------------- transpose (f16/f32, padded rows)
struct TPlanX { const float* src; void* dst; int R, C, blk0, isf16, pad; };
struct TPlansX { TPlanX p[24]; int n; };

__global__ void transpose_x(TPlansX P) {
    int b = blockIdx.x;
    int pi = 0;
#pragma unroll
    for (int i = 1; i < 24; ++i)
        if (i < P.n && b >= P.p[i].blk0) pi = i;
    const float* src = P.p[pi].src;
    int R = P.p[pi].R, C = P.p[pi].C, pad = P.p[pi].pad;
    int f = (b - P.p[pi].blk0) * 256 + threadIdx.x;
    if (f < R * C) {
        int c = f / R, r = f - c * R;
        float val = src[r * C + c];
        if (P.p[pi].isf16) ((_Float16*)P.p[pi].dst)[c * pad + r] = (_Float16)val;
        else ((float*)P.p[pi].dst)[c * pad + r] = val;
    }
}

// ---------------------------------------------------------------- phiMLP (layer 0 only) -> pv phi slots
__global__ __launch_bounds__(256) void phi_mlp_kernel(
    const _Float16* __restrict__ s_h, const _Float16* __restrict__ w1T,
    const float* __restrict__ b1, const _Float16* __restrict__ w2T,
    const float* __restrict__ b2, _Float16* __restrict__ pv) {
    __shared__ __align__(16) _Float16 shA[16 * 136];
    __shared__ __align__(16) _Float16 shH[16 * 136];
    int r0 = blockIdx.x * 16;
    int tid = threadIdx.x;
    {
        int r = tid >> 4, c8 = (tid & 15) * 8;
        int rg = r0 + r; if (rg >= N_ATOMS) rg = N_ATOMS - 1;
        *(f16x8*)(shA + r * 136 + c8) = *(const f16x8*)(s_h + (size_t)rg * F + c8);
    }
    __syncthreads();
    int lane = tid & 63, wv = tid >> 6;
    int col = lane & 15, quad = lane >> 4;
    for (int nt = wv; nt < 8; nt += 4) {
        int n = nt * 16 + col;
        f32x4 acc = {0.f, 0.f, 0.f, 0.f};
#pragma unroll
        for (int kt = 0; kt < 4; ++kt) {
            f16x8 afr = *(const f16x8*)(shA + col * 136 + kt * 32 + quad * 8);
            f16x8 bfr = *(const f16x8*)(w1T + (size_t)n * 128 + kt * 32 + quad * 8);
            acc = __builtin_amdgcn_mfma_f32_16x16x32_f16(afr, bfr, acc, 0, 0, 0);
        }
        float bb = b1[n];
#pragma unroll
        for (int r = 0; r < 4; ++r)
            shH[(quad * 4 + r) * 136 + n] = (_Float16)silu_f(acc[r] + bb);
    }
    __syncthreads();
    for (int nt = wv; nt < 24; nt += 4) {
        int n = nt * 16 + col;
        f32x4 acc = {0.f, 0.f, 0.f, 0.f};
#pragma unroll
        for (int kt = 0; kt < 4; ++kt) {
            f16x8 afr = *(const f16x8*)(shH + col * 136 + kt * 32 + quad * 8);
            f16x8 bfr = *(const f16x8*)(w2T + (size_t)n * 128 + kt * 32 + quad * 8);
            acc = __builtin_amdgcn_mfma_f32_16x16x32_f16(afr, bfr, acc, 0, 0, 0);
        }
        float bb = b2[n];
#pragma unroll
        for (int r = 0; r < 4; ++r) {
            int row = r0 + quad * 4 + r;
            if (row < N_ATOMS)
                pv[PV_IDX(row, n & 127) + (n >> 7)] = (_Float16)(acc[r] + bb);
        }
    }
}

// ---------------------------------------------------------------- per-dst edge aggregation
// 512 threads = 4 edge-teams x 128 feature threads; single 12B pv gather per edge.
__global__ __launch_bounds__(512) void edge_agg_kernel(
    const int* __restrict__ count, const EMeta* __restrict__ meta,
    const _Float16* __restrict__ rbfh,
    const _Float16* __restrict__ fwT,   // [384][24] f16
    const float* __restrict__ fb,
    const _Float16* __restrict__ pv,
    float* __restrict__ s, float* __restrict__ v,
    _Float16* __restrict__ vmid_h) {
    int a = blockIdx.x;
    int tid = threadIdx.x;
    int t = tid & 127;
    int team = tid >> 7;   // 0..3

    unsigned int rw0[10], rw1[10], rw2[10];
    {
        const unsigned int* p0 = (const unsigned int*)(fwT + (size_t)t * 24);
        const unsigned int* p1 = (const unsigned int*)(fwT + (size_t)(F + t) * 24);
        const unsigned int* p2 = (const unsigned int*)(fwT + (size_t)(2 * F + t) * 24);
#pragma unroll
        for (int j = 0; j < 10; ++j) { rw0[j] = p0[j]; rw1[j] = p1[j]; rw2[j] = p2[j]; }
    }
    float fb0 = fb[t], fb1 = fb[F + t], fb2 = fb[2 * F + t];

    int n = count[a]; if (n > CAP) n = CAP;
    float accS = 0.f, accV0 = 0.f, accV1 = 0.f, accV2 = 0.f;

    __shared__ int sh_src[32];
    __shared__ float sh_env[32];
    __shared__ float sh_unit[32][3];
    __shared__ __align__(16) unsigned int sh_rbf[32 * 12];
    __shared__ __align__(16) float sh_part[3][4][F];
    const size_t aC = (size_t)a * CAP;
    const unsigned int* rbf32 = (const unsigned int*)rbfh;

    for (int base = 0; base < n; base += 32) {
        int cnt = min(32, n - base);
        __syncthreads();
        if (tid < cnt) {
            EMeta m = meta[aC + base + tid];
            sh_src[tid] = m.src;
            sh_env[tid] = m.env;
            sh_unit[tid][0] = m.u0; sh_unit[tid][1] = m.u1; sh_unit[tid][2] = m.u2;
        }
        for (int task = tid; task < cnt * 12; task += 512) {
            int i = task / 12, w = task - i * 12;
            sh_rbf[i * 12 + w] = rbf32[(aC + base + i) * 12 + w];
        }
        __syncthreads();

        int myCnt = (cnt > team) ? ((cnt - team + 3) >> 2) : 0;
        if (myCnt > 0) {
            U3 QA[4], QB[4];
            int ngrp = (myCnt + 3) >> 2;

            auto load_grp = [&](int gbase, U3 Q[4]) {
#pragma unroll
                for (int j = 0; j < 4; ++j) {
                    int i = gbase + j;
                    int ii = (i < myCnt) ? i : (myCnt - 1);
                    int src = sh_src[team + 4 * ii];
                    Q[j] = *(const U3*)(pv + PV_IDX(src, t));
                }
            };
            auto comp_grp = [&](int gbase, U3 Q[4]) {
#pragma unroll
                for (int j = 0; j < 4; ++j) {
                    int i = gbase + j;
                    if (i < myCnt) {
                        int ei = team + 4 * i;
                        const uint4* rq = (const uint4*)(sh_rbf + ei * 12);
                        uint4 qa = rq[0], qb = rq[1];
                        uint2 qc = *(const uint2*)(sh_rbf + ei * 12 + 8);
                        unsigned int rr[10] = {qa.x, qa.y, qa.z, qa.w,
                                               qb.x, qb.y, qb.z, qb.w, qc.x, qc.y};
                        float f0 = fb0, f1 = fb1, f2 = fb2;
#pragma unroll
                        for (int p = 0; p < 10; ++p) {
                            h2 rb = __builtin_bit_cast(h2, rr[p]);
                            f0 = __builtin_amdgcn_fdot2(rb, __builtin_bit_cast(h2, rw0[p]), f0, false);
                            f1 = __builtin_amdgcn_fdot2(rb, __builtin_bit_cast(h2, rw1[p]), f1, false);
                            f2 = __builtin_amdgcn_fdot2(rb, __builtin_bit_cast(h2, rw2[p]), f2, false);
                        }
                        float env = sh_env[ei];
                        f0 *= env; f1 *= env; f2 *= env;
                        h2 q0 = __builtin_bit_cast(h2, Q[j].x);   // phi0, phi1
                        h2 q1 = __builtin_bit_cast(h2, Q[j].y);   // phi2, v0
                        h2 q2 = __builtin_bit_cast(h2, Q[j].z);   // v1, v2
                        accS += f2 * (float)q1[0];
                        float gsv = f0 * (float)q0[0];
                        float gev = f1 * (float)q0[1];
                        accV0 += (float)q1[1] * gsv + gev * sh_unit[ei][0];
                        accV1 += (float)q2[0] * gsv + gev * sh_unit[ei][1];
                        accV2 += (float)q2[1] * gsv + gev * sh_unit[ei][2];
                    }
                }
            };

            load_grp(0, QA);
            for (int g = 0; g < ngrp; g += 2) {
                if (g + 1 < ngrp) load_grp((g + 1) * 4, QB);
                comp_grp(g * 4, QA);
                if (g + 1 < ngrp) {
                    if (g + 2 < ngrp) load_grp((g + 2) * 4, QA);
                    comp_grp((g + 1) * 4, QB);
                }
            }
        }
    }

    __syncthreads();
    if (team >= 1) {
        sh_part[team - 1][0][t] = accS; sh_part[team - 1][1][t] = accV0;
        sh_part[team - 1][2][t] = accV1; sh_part[team - 1][3][t] = accV2;
    }
    __syncthreads();
    if (team == 0) {
        float sm = s[a * F + t] + accS + sh_part[0][0][t] + sh_part[1][0][t] + sh_part[2][0][t];
        s[a * F + t] = sm;
        float vm0 = v[a * 3 * F + t] + accV0 + sh_part[0][1][t] + sh_part[1][1][t] + sh_part[2][1][t];
        float vm1 = v[a * 3 * F + F + t] + accV1 + sh_part[0][2][t] + sh_part[1][2][t] + sh_part[2][2][t];
        float vm2 = v[a * 3 * F + 2 * F + t] + accV2 + sh_part[0][3][t] + sh_part[1][3][t] + sh_part[2][3][t];
        v[a * 3 * F + t] = vm0;
        v[a * 3 * F + F + t] = vm1;
        v[a * 3 * F + 2 * F + t] = vm2;
        vmid_h[(size_t)(a * 3 + 0) * F + t] = (_Float16)vm0;
        vmid_h[(size_t)(a * 3 + 1) * F + t] = (_Float16)vm1;
        vmid_h[(size_t)(a * 3 + 2) * F + t] = (_Float16)vm2;
    }
}

// ---------------------------------------------------------------- fused update, TA=16, 512 threads (8 waves)
__global__ __launch_bounds__(512) void fused_update_kernel(
    const _Float16* __restrict__ vmid_h, const _Float16* __restrict__ uvT,
    const _Float16* __restrict__ w1T, const float* __restrict__ b1,
    const _Float16* __restrict__ w2T, const float* __restrict__ b2,
    float* __restrict__ s, float* __restrict__ v, _Float16* __restrict__ pv,
    const _Float16* __restrict__ nw1T, const float* __restrict__ nb1,
    const _Float16* __restrict__ nw2T, const float* __restrict__ nb2,
    int do_phi,
    const _Float16* __restrict__ roT16, const float* __restrict__ rb1,
    const float* __restrict__ rw2, const float* __restrict__ rb2,
    float* __restrict__ out, int do_ro) {
    __shared__ __align__(16) _Float16 shA[48 * 136];    // vmid tile; reused as s-tile
    __shared__ __align__(16) _Float16 shUV[48 * 264];
    __shared__ __align__(16) _Float16 shCat[16 * 264];
    __shared__ __align__(16) _Float16 shH[16 * 136];
    __shared__ __align__(16) _Float16 shAa[16 * 392];
    _Float16* shS = shA;
    float* shRO = (float*)shAa;   // 16 x 68 f32 (alias, used only in do_ro after barrier)
    int a0 = blockIdx.x * 16;
    int r0 = a0 * 3;
    int tid = threadIdx.x;
    for (int slot = tid; slot < 48 * 16; slot += 512) {
        int r = slot >> 4, c8 = (slot & 15) * 8;
        int rg = r0 + r; if (rg >= N_ATOMS * 3) rg = N_ATOMS * 3 - 1;
        *(f16x8*)(shA + r * 136 + c8) = *(const f16x8*)(vmid_h + (size_t)rg * F + c8);
    }
    __syncthreads();
    int lane = tid & 63, wv = tid >> 6;   // wv in [0,8)
    int col = lane & 15, quad = lane >> 4;

    // stage 1: UV = vmid @ [U|V]
    for (int j = wv; j < 48; j += 8) {
        int mt = j >> 4, nt = j & 15;
        int n = nt * 16 + col;
        f32x4 acc = {0.f, 0.f, 0.f, 0.f};
#pragma unroll
        for (int kt = 0; kt < 4; ++kt) {
            f16x8 afr = *(const f16x8*)(shA + (mt * 16 + col) * 136 + kt * 32 + quad * 8);
            f16x8 bfr = *(const f16x8*)(uvT + (size_t)n * 128 + kt * 32 + quad * 8);
            acc = __builtin_amdgcn_mfma_f32_16x16x32_f16(afr, bfr, acc, 0, 0, 0);
        }
#pragma unroll
        for (int r = 0; r < 4; ++r)
            shUV[(mt * 16 + quad * 4 + r) * 264 + n] = (_Float16)acc[r];
    }
    __syncthreads();

    // stage 2: concat = [s, Vn]
    for (int p = tid; p < 2048; p += 512) {
        int ai = p >> 7, t = p & 127;
        int atom = a0 + ai;
        int ag = (atom < N_ATOMS) ? atom : N_ATOMS - 1;
        shCat[ai * 264 + t] = (_Float16)s[(size_t)ag * F + t];
        float x0 = (float)shUV[(ai * 3 + 0) * 264 + 128 + t];
        float x1 = (float)shUV[(ai * 3 + 1) * 264 + 128 + t];
        float x2 = (float)shUV[(ai * 3 + 2) * 264 + 128 + t];
        shCat[ai * 264 + 128 + t] = (_Float16)sqrtf(x0 * x0 + x1 * x1 + x2 * x2);
    }
    __syncthreads();

    // stage 3: hidden = silu(concat @ w1 + b1), K=256
    for (int nt = wv; nt < 8; nt += 8) {
        int n = nt * 16 + col;
        f32x4 acc = {0.f, 0.f, 0.f, 0.f};
#pragma unroll
        for (int kt = 0; kt < 8; ++kt) {
            f16x8 afr = *(const f16x8*)(shCat + col * 264 + kt * 32 + quad * 8);
            f16x8 bfr = *(const f16x8*)(w1T + (size_t)n * 256 + kt * 32 + quad * 8);
            acc = __builtin_amdgcn_mfma_f32_16x16x32_f16(afr, bfr, acc, 0, 0, 0);
        }
        float bb = b1[n];
#pragma unroll
        for (int r = 0; r < 4; ++r)
            shH[(quad * 4 + r) * 136 + n] = (_Float16)silu_f(acc[r] + bb);
    }
    __syncthreads();

    // stage 4: a = hidden @ w2 + b2
    for (int nt = wv; nt < 24; nt += 8) {
        int n = nt * 16 + col;
        f32x4 acc = {0.f, 0.f, 0.f, 0.f};
#pragma unroll
        for (int kt = 0; kt < 4; ++kt) {
            f16x8 afr = *(const f16x8*)(shH + col * 136 + kt * 32 + quad * 8);
            f16x8 bfr = *(const f16x8*)(w2T + (size_t)n * 128 + kt * 32 + quad * 8);
            acc = __builtin_amdgcn_mfma_f32_16x16x32_f16(afr, bfr, acc, 0, 0, 0);
        }
        float bb = b2[n];
#pragma unroll
        for (int r = 0; r < 4; ++r)
            shAa[(quad * 4 + r) * 392 + n] = (_Float16)(acc[r] + bb);
    }
    __syncthreads();

    // stage 5: final elementwise update; new s into shS (f16), new v into pv[3..5]
    for (int p = tid; p < 2048; p += 512) {
        int ai = p >> 7, t = p & 127;
        int atom = a0 + ai;
        if (atom >= N_ATOMS) { shS[ai * 136 + t] = (_Float16)0.0f; continue; }
        float avv = (float)shAa[ai * 392 + t];
        float asv = (float)shAa[ai * 392 + 128 + t];
        float ass = (float)shAa[ai * 392 + 256 + t];
        float dot = 0.f;
        _Float16* pvp = pv + PV_IDX(atom, t);
#pragma unroll
        for (int d = 0; d < 3; ++d) {
            float u = (float)shUV[(ai * 3 + d) * 264 + t];
            float w = (float)shUV[(ai * 3 + d) * 264 + 128 + t];
            dot += u * w;
            float nv = v[(size_t)atom * 3 * F + d * F + t] + avv * u;
            v[(size_t)atom * 3 * F + d * F + t] = nv;
            pvp[3 + d] = (_Float16)nv;
        }
        float sn = s[(size_t)atom * F + t] + asv * dot + ass;
        s[(size_t)atom * F + t] = sn;
        shS[ai * 136 + t] = (_Float16)sn;
    }

    // stage 6a: next layer's phi -> pv[0..2]
    if (do_phi) {
        __syncthreads();
        for (int nt = wv; nt < 8; nt += 8) {
            int n = nt * 16 + col;
            f32x4 acc = {0.f, 0.f, 0.f, 0.f};
#pragma unroll
            for (int kt = 0; kt < 4; ++kt) {
                f16x8 afr = *(const f16x8*)(shS + col * 136 + kt * 32 + quad * 8);
                f16x8 bfr = *(const f16x8*)(nw1T + (size_t)n * 128 + kt * 32 + quad * 8);
                acc = __builtin_amdgcn_mfma_f32_16x16x32_f16(afr, bfr, acc, 0, 0, 0);
            }
            float bb = nb1[n];
#pragma unroll
            for (int r = 0; r < 4; ++r)
                shH[(quad * 4 + r) * 136 + n] = (_Float16)silu_f(acc[r] + bb);
        }
        __syncthreads();
        for (int nt = wv; nt < 24; nt += 8) {
            int n = nt * 16 + col;
            f32x4 acc = {0.f, 0.f, 0.f, 0.f};
#pragma unroll
            for (int kt = 0; kt < 4; ++kt) {
                f16x8 afr = *(const f16x8*)(shH + col * 136 + kt * 32 + quad * 8);
                f16x8 bfr = *(const f16x8*)(nw2T + (size_t)n * 128 + kt * 32 + quad * 8);
                acc = __builtin_amdgcn_mfma_f32_16x16x32_f16(afr, bfr, acc, 0, 0, 0);
            }
            float bb = nb2[n];
#pragma unroll
            for (int r = 0; r < 4; ++r) {
                int row = a0 + quad * 4 + r;
                if (row < N_ATOMS)
                    pv[PV_IDX(row, n & 127) + (n >> 7)] = (_Float16)(acc[r] + bb);
            }
        }
    }

    // stage 6b: readout (last layer)
    if (do_ro) {
        __syncthreads();
        if (wv < 4) {
            int n = wv * 16 + col;   // n in [0,64)
            f32x4 acc = {0.f, 0.f, 0.f, 0.f};
#pragma unroll
            for (int kt = 0; kt < 4; ++kt) {
                f16x8 afr = *(const f16x8*)(shS + col * 136 + kt * 32 + quad * 8);
                f16x8 bfr = *(const f16x8*)(roT16 + (size_t)n * 128 + kt * 32 + quad * 8);
                acc = __builtin_amdgcn_mfma_f32_16x16x32_f16(afr, bfr, acc, 0, 0, 0);
            }
            float bb = rb1[n], w2n = rw2[n];
#pragma unroll
            for (int r = 0; r < 4; ++r)
                shRO[(quad * 4 + r) * 68 + n] = silu_f(acc[r] + bb) * w2n;
        }
        __syncthreads();
        if (tid < 16) {
            int atom = a0 + tid;
            if (atom < N_ATOMS) {
                float sum = rb2[0];
#pragma unroll 8
                for (int k = 0; k < 64; ++k) sum += shRO[tid * 68 + k];
                out[atom] = sum;
            }
        }
    }
}

extern "C" void kernel_launch(void* const* d_in, const int* in_sizes, int n_in,
                              void* d_out, int out_size, void* d_ws, size_t ws_size,
                              hipStream_t stream) {
    const int*   Z      = (const int*)d_in[0];
    const int*   eidx   = (const int*)d_in[1];
    const float* ediff  = (const float*)d_in[2];
    const float* edist  = (const float*)d_in[3];
    const float* emb    = (const float*)d_in[4];
    const float* msg_w1 = (const float*)d_in[5];
    const float* msg_b1 = (const float*)d_in[6];
    const float* msg_w2 = (const float*)d_in[7];
    const float* msg_b2 = (const float*)d_in[8];
    const float* filt_w = (const float*)d_in[9];
    const float* filt_b = (const float*)d_in[10];
    const float* upd_U  = (const float*)d_in[11];
    const float* upd_V  = (const float*)d_in[12];
    const float* upd_w1 = (const float*)d_in[13];
    const float* upd_b1 = (const float*)d_in[14];
    const float* upd_w2 = (const float*)d_in[15];
    const float* upd_b2 = (const float*)d_in[16];
    const float* ro_w1  = (const float*)d_in[17];
    const float* ro_b1  = (const float*)d_in[18];
    const float* ro_w2  = (const float*)d_in[19];
    const float* ro_b2  = (const float*)d_in[20];
    float* out = (float*)d_out;

    // ---------------- workspace layout ----------------
    float* ws = (float*)d_ws;
    float* s   = ws;                      // N*F f32
    float* v   = s + N_ATOMS * F;         // N*3F f32
    int* count  = (int*)(v + N_ATOMS * 3 * F);   // N
    int* bucket = count + N_ATOMS;               // N*CAP
    EMeta* meta = (EMeta*)(bucket + N_ATOMS * CAP);           // N*CAP*32B
    _Float16* rbfh = (_Float16*)(meta + N_ATOMS * CAP);       // N*CAP*24
    _Float16* s_h    = rbfh + (size_t)N_ATOMS * CAP * 24;     // N*F
    _Float16* vmid_h = s_h + (size_t)N_ATOMS * F;             // N*3F
    _Float16* pv     = vmid_h + (size_t)N_ATOMS * 3 * F;      // N*F*6
    _Float16* wh     = pv + (size_t)N_ATOMS * F * 6;          // f16 weights

    const int HWL = 16384 + 49152 + 32768 + 32768 + 49152 + 384 * 24;
    _Float16* mw1T = wh;                   // [128][128]
    _Float16* mw2T = wh + 16384;           // [384][128]
    _Float16* uvT  = wh + 65536;           // [256][128]
    _Float16* uw1T = wh + 98304;           // [128][256]
    _Float16* uw2T = wh + 131072;          // [384][128]
    _Float16* fwTl = wh + 180224;          // [384][24]
    _Float16* roT16 = wh + (size_t)NL * HWL;  // [64][128]

    // ---------------- transpose plan ----------------
    TPlansX P; int nb = 0, pi = 0;
    auto add = [&](const float* src, void* dst, int R, int C, int isf16, int pad) {
        P.p[pi].src = src; P.p[pi].dst = dst; P.p[pi].R = R; P.p[pi].C = C;
        P.p[pi].blk0 = nb; P.p[pi].isf16 = isf16; P.p[pi].pad = pad;
        nb += (R * C + 255) / 256; ++pi;
    };
    for (int l = 0; l < NL; ++l) {
        add(msg_w1 + l * F * F,     mw1T + (size_t)l * HWL, F, F, 1, F);
        add(msg_w2 + l * F * 3 * F, mw2T + (size_t)l * HWL, F, 3 * F, 1, F);
        add(upd_U  + l * F * F,     uvT  + (size_t)l * HWL, F, F, 1, F);
        add(upd_V  + l * F * F,     uvT  + (size_t)l * HWL + F * F, F, F, 1, F);
        add(upd_w1 + l * 2 * F * F, uw1T + (size_t)l * HWL, 2 * F, F, 1, 2 * F);
        add(upd_w2 + l * F * 3 * F, uw2T + (size_t)l * HWL, F, 3 * F, 1, F);
        add(filt_w + l * B * 3 * F, fwTl + (size_t)l * HWL, B, 3 * F, 1, 24);
    }
    add(ro_w1, roT16, F, 64, 1, F);
    P.n = pi;

    // ---------------- launch ----------------
    init_kernel<<<N_ATOMS, F, 0, stream>>>(Z, emb, s, s_h, v, pv, count);
    fill_buckets<<<(N_EDGES + 255) / 256, 256, 0, stream>>>(eidx, count, bucket);
    transpose_x<<<nb, 256, 0, stream>>>(P);
    edge_meta_kernel<<<(N_ATOMS * CAP + 255) / 256, 256, 0, stream>>>(
        count, bucket, eidx, ediff, edist, meta, rbfh);

    const int GB16 = (N_ATOMS + 15) / 16;   // 313
    phi_mlp_kernel<<<GB16, 256, 0, stream>>>(
        s_h, mw1T, msg_b1, mw2T, msg_b2, pv);
    for (int l = 0; l < NL; ++l) {
        edge_agg_kernel<<<N_ATOMS, 512, 0, stream>>>(
            count, meta, rbfh, fwTl + (size_t)l * HWL, filt_b + l * 3 * F,
            pv, s, v, vmid_h);
        int do_phi = (l + 1 < NL);
        int do_ro = (l == NL - 1);
        int ln = do_phi ? (l + 1) : l;
        fused_update_kernel<<<GB16, 512, 0, stream>>>(
            vmid_h, uvT + (size_t)l * HWL,
            uw1T + (size_t)l * HWL, upd_b1 + l * F,
            uw2T + (size_t)l * HWL, upd_b2 + l * 3 * F,
            s, v, pv,
            mw1T + (size_t)ln * HWL, msg_b1 + ln * F,
            mw2T + (size_t)ln * HWL, msg_b2 + ln * 3 * F, do_phi,
            roT16, ro_b1, ro_w2, ro_b2, out, do_ro);
    }
}

// Round 16
// 358.340 us; speedup vs baseline: 1.1113x; 1.1113x over previous
//
#include <hip/hip_runtime.h>
#include <hip/hip_bf16.h>
#include <hip/hip_fp16.h>
#include <math.h>

#define N_ATOMS 5000
#define N_EDGES 100000
#define F 128
#define B 20
#define NL 3
#define CAP 64

constexpr float CUTOFF = 5.0f;
constexpr float PI_F = 3.14159265358979323846f;

typedef _Float16 f16x8 __attribute__((ext_vector_type(8)));
typedef _Float16 h2 __attribute__((ext_vector_type(2)));
typedef float f32x4 __attribute__((ext_vector_type(4)));

struct EMeta { int src; float env; float u0, u1, u2; int pad[3]; };  // 32 B
struct __align__(4) U3 { unsigned int x, y, z; };                    // 12 B pv record

__device__ __forceinline__ float silu_f(float x) { return x / (1.0f + __expf(-x)); }

// pv layout: per (atom, t): [phi0, phi1, phi2, v0, v1, v2] f16 (12 B)
#define PV_IDX(atom, t) (((size_t)(atom) * F + (t)) * 6)

// ---------------------------------------------------------------- init
__global__ void init_kernel(const int* __restrict__ Z, const float* __restrict__ emb,
                            float* __restrict__ s, _Float16* __restrict__ s_h,
                            float* __restrict__ v, _Float16* __restrict__ pv,
                            int* __restrict__ count) {
    int atom = blockIdx.x;
    int t = threadIdx.x;
    float val = emb[Z[atom] * F + t];
    s[atom * F + t] = val;
    s_h[atom * F + t] = (_Float16)val;
#pragma unroll
    for (int d = 0; d < 3; ++d) v[(size_t)atom * 3 * F + d * F + t] = 0.0f;
    unsigned int* pp = (unsigned int*)(pv + PV_IDX(atom, t));
    pp[0] = 0u; pp[1] = 0u; pp[2] = 0u;
    if (t == 0) count[atom] = 0;
}

// ---------------------------------------------------------------- bucket edges by dst
__global__ void fill_buckets(const int* __restrict__ eidx, int* __restrict__ count,
                             int* __restrict__ bucket) {
    int e = blockIdx.x * 256 + threadIdx.x;
    if (e >= N_EDGES) return;
    int dst = eidx[2 * e];
    int pos = atomicAdd(&count[dst], 1);
    if (pos < CAP) bucket[dst * CAP + pos] = e;
}

// ---------------------------------------------------------------- per-slot edge metadata
__global__ void edge_meta_kernel(const int* __restrict__ count, const int* __restrict__ bucket,
                                 const int* __restrict__ eidx, const float* __restrict__ ediff,
                                 const float* __restrict__ edist,
                                 EMeta* __restrict__ meta, _Float16* __restrict__ rbfh) {
    int slot = blockIdx.x * 256 + threadIdx.x;
    if (slot >= N_ATOMS * CAP) return;
    int a = slot / CAP, i = slot % CAP;
    if (i >= count[a]) return;
    int e = bucket[slot];
    float d = edist[e];
    EMeta m;
    m.src = eidx[2 * e + 1];
    float fc = 0.5f * (cosf(PI_F * d / CUTOFF) + 1.0f);
    m.env = (d < CUTOFF) ? fc : 0.0f;
    float inv = 1.0f / d;
    m.u0 = ediff[3 * e + 0] * inv;
    m.u1 = ediff[3 * e + 1] * inv;
    m.u2 = ediff[3 * e + 2] * inv;
    m.pad[0] = m.pad[1] = m.pad[2] = 0;
    meta[slot] = m;
    _Float16* rp = rbfh + (size_t)slot * 24;
#pragma unroll
    for (int b = 0; b < B; ++b)
        rp[b] = (_Float16)(sinf(d * (float)(b + 1) * (PI_F / CUTOFF)) / d);
    rp[20] = rp[21] = rp[22] = rp[23] = (_Float16)0.0f;
}

// ---------------------------------------------------------------- transpose (f16/f32, padded rows)
struct TPlanX { const float* src; void* dst; int R, C, blk0, isf16, pad; };
struct TPlansX { TPlanX p[24]; int n; };

__global__ void transpose_x(TPlansX P) {
    int b = blockIdx.x;
    int pi = 0;
#pragma unroll
    for (int i = 1; i < 24; ++i)
        if (i < P.n && b >= P.p[i].blk0) pi = i;
    const float* src = P.p[pi].src;
    int R = P.p[pi].R, C = P.p[pi].C, pad = P.p[pi].pad;
    int f = (b - P.p[pi].blk0) * 256 + threadIdx.x;
    if (f < R * C) {
        int c = f / R, r = f - c * R;
        float val = src[r * C + c];
        if (P.p[pi].isf16) ((_Float16*)P.p[pi].dst)[c * pad + r] = (_Float16)val;
        else ((float*)P.p[pi].dst)[c * pad + r] = val;
    }
}

// ---------------------------------------------------------------- phiMLP (layer 0 only) -> pv phi slots
__global__ __launch_bounds__(256) void phi_mlp_kernel(
    const _Float16* __restrict__ s_h, const _Float16* __restrict__ w1T,
    const float* __restrict__ b1, const _Float16* __restrict__ w2T,
    const float* __restrict__ b2, _Float16* __restrict__ pv) {
    __shared__ __align__(16) _Float16 shA[16 * 136];
    __shared__ __align__(16) _Float16 shH[16 * 136];
    int r0 = blockIdx.x * 16;
    int tid = threadIdx.x;
    {
        int r = tid >> 4, c8 = (tid & 15) * 8;
        int rg = r0 + r; if (rg >= N_ATOMS) rg = N_ATOMS - 1;
        *(f16x8*)(shA + r * 136 + c8) = *(const f16x8*)(s_h + (size_t)rg * F + c8);
    }
    __syncthreads();
    int lane = tid & 63, wv = tid >> 6;
    int col = lane & 15, quad = lane >> 4;
    for (int nt = wv; nt < 8; nt += 4) {
        int n = nt * 16 + col;
        f32x4 acc = {0.f, 0.f, 0.f, 0.f};
#pragma unroll
        for (int kt = 0; kt < 4; ++kt) {
            f16x8 afr = *(const f16x8*)(shA + col * 136 + kt * 32 + quad * 8);
            f16x8 bfr = *(const f16x8*)(w1T + (size_t)n * 128 + kt * 32 + quad * 8);
            acc = __builtin_amdgcn_mfma_f32_16x16x32_f16(afr, bfr, acc, 0, 0, 0);
        }
        float bb = b1[n];
#pragma unroll
        for (int r = 0; r < 4; ++r)
            shH[(quad * 4 + r) * 136 + n] = (_Float16)silu_f(acc[r] + bb);
    }
    __syncthreads();
    for (int nt = wv; nt < 24; nt += 4) {
        int n = nt * 16 + col;
        f32x4 acc = {0.f, 0.f, 0.f, 0.f};
#pragma unroll
        for (int kt = 0; kt < 4; ++kt) {
            f16x8 afr = *(const f16x8*)(shH + col * 136 + kt * 32 + quad * 8);
            f16x8 bfr = *(const f16x8*)(w2T + (size_t)n * 128 + kt * 32 + quad * 8);
            acc = __builtin_amdgcn_mfma_f32_16x16x32_f16(afr, bfr, acc, 0, 0, 0);
        }
        float bb = b2[n];
#pragma unroll
        for (int r = 0; r < 4; ++r) {
            int row = r0 + quad * 4 + r;
            if (row < N_ATOMS)
                pv[PV_IDX(row, n & 127) + (n >> 7)] = (_Float16)(acc[r] + bb);
        }
    }
}

// ---------------------------------------------------------------- per-dst edge aggregation
// round-14 proven structure: 256 threads = 2 edge-teams; 12B pv gather per edge.
__global__ __launch_bounds__(256) void edge_agg_kernel(
    const int* __restrict__ count, const EMeta* __restrict__ meta,
    const _Float16* __restrict__ rbfh,
    const _Float16* __restrict__ fwT,   // [384][24] f16
    const float* __restrict__ fb,
    const _Float16* __restrict__ pv,
    float* __restrict__ s, float* __restrict__ v,
    _Float16* __restrict__ vmid_h) {
    int a = blockIdx.x;
    int tid = threadIdx.x;
    int t = tid & 127;
    int team = tid >> 7;   // 0..1

    unsigned int rw0[10], rw1[10], rw2[10];
    {
        const unsigned int* p0 = (const unsigned int*)(fwT + (size_t)t * 24);
        const unsigned int* p1 = (const unsigned int*)(fwT + (size_t)(F + t) * 24);
        const unsigned int* p2 = (const unsigned int*)(fwT + (size_t)(2 * F + t) * 24);
#pragma unroll
        for (int j = 0; j < 10; ++j) { rw0[j] = p0[j]; rw1[j] = p1[j]; rw2[j] = p2[j]; }
    }
    float fb0 = fb[t], fb1 = fb[F + t], fb2 = fb[2 * F + t];

    int n = count[a]; if (n > CAP) n = CAP;
    float accS = 0.f, accV0 = 0.f, accV1 = 0.f, accV2 = 0.f;

    __shared__ int sh_src[32];
    __shared__ float sh_env[32];
    __shared__ float sh_unit[32][3];
    __shared__ __align__(16) unsigned int sh_rbf[32 * 12];
    __shared__ __align__(16) float sh_part[4][F];
    const size_t aC = (size_t)a * CAP;
    const unsigned int* rbf32 = (const unsigned int*)rbfh;

    for (int base = 0; base < n; base += 32) {
        int cnt = min(32, n - base);
        __syncthreads();
        if (tid < cnt) {
            EMeta m = meta[aC + base + tid];
            sh_src[tid] = m.src;
            sh_env[tid] = m.env;
            sh_unit[tid][0] = m.u0; sh_unit[tid][1] = m.u1; sh_unit[tid][2] = m.u2;
        }
        for (int task = tid; task < cnt * 12; task += 256) {
            int i = task / 12, w = task - i * 12;
            sh_rbf[i * 12 + w] = rbf32[(aC + base + i) * 12 + w];
        }
        __syncthreads();

        int myCnt = (cnt > team) ? ((cnt - team + 1) >> 1) : 0;
        if (myCnt > 0) {
            U3 QA[4], QB[4];
            int ngrp = (myCnt + 3) >> 2;

            auto load_grp = [&](int gbase, U3 Q[4]) {
#pragma unroll
                for (int j = 0; j < 4; ++j) {
                    int i = gbase + j;
                    int ii = (i < myCnt) ? i : (myCnt - 1);
                    int src = sh_src[team + 2 * ii];
                    Q[j] = *(const U3*)(pv + PV_IDX(src, t));
                }
            };
            auto comp_grp = [&](int gbase, U3 Q[4]) {
#pragma unroll
                for (int j = 0; j < 4; ++j) {
                    int i = gbase + j;
                    if (i < myCnt) {
                        int ei = team + 2 * i;
                        const uint4* rq = (const uint4*)(sh_rbf + ei * 12);
                        uint4 qa = rq[0], qb = rq[1];
                        uint2 qc = *(const uint2*)(sh_rbf + ei * 12 + 8);
                        unsigned int rr[10] = {qa.x, qa.y, qa.z, qa.w,
                                               qb.x, qb.y, qb.z, qb.w, qc.x, qc.y};
                        float f0 = fb0, f1 = fb1, f2 = fb2;
#pragma unroll
                        for (int p = 0; p < 10; ++p) {
                            h2 rb = __builtin_bit_cast(h2, rr[p]);
                            f0 = __builtin_amdgcn_fdot2(rb, __builtin_bit_cast(h2, rw0[p]), f0, false);
                            f1 = __builtin_amdgcn_fdot2(rb, __builtin_bit_cast(h2, rw1[p]), f1, false);
                            f2 = __builtin_amdgcn_fdot2(rb, __builtin_bit_cast(h2, rw2[p]), f2, false);
                        }
                        float env = sh_env[ei];
                        f0 *= env; f1 *= env; f2 *= env;
                        h2 q0 = __builtin_bit_cast(h2, Q[j].x);   // phi0, phi1
                        h2 q1 = __builtin_bit_cast(h2, Q[j].y);   // phi2, v0
                        h2 q2 = __builtin_bit_cast(h2, Q[j].z);   // v1, v2
                        accS += f2 * (float)q1[0];
                        float gsv = f0 * (float)q0[0];
                        float gev = f1 * (float)q0[1];
                        accV0 += (float)q1[1] * gsv + gev * sh_unit[ei][0];
                        accV1 += (float)q2[0] * gsv + gev * sh_unit[ei][1];
                        accV2 += (float)q2[1] * gsv + gev * sh_unit[ei][2];
                    }
                }
            };

            load_grp(0, QA);
            for (int g = 0; g < ngrp; g += 2) {
                if (g + 1 < ngrp) load_grp((g + 1) * 4, QB);
                comp_grp(g * 4, QA);
                if (g + 1 < ngrp) {
                    if (g + 2 < ngrp) load_grp((g + 2) * 4, QA);
                    comp_grp((g + 1) * 4, QB);
                }
            }
        }
    }

    __syncthreads();
    if (team == 1) {
        sh_part[0][t] = accS; sh_part[1][t] = accV0;
        sh_part[2][t] = accV1; sh_part[3][t] = accV2;
    }
    __syncthreads();
    if (team == 0) {
        float sm = s[a * F + t] + accS + sh_part[0][t];
        s[a * F + t] = sm;
        float vm0 = v[a * 3 * F + t] + accV0 + sh_part[1][t];
        float vm1 = v[a * 3 * F + F + t] + accV1 + sh_part[2][t];
        float vm2 = v[a * 3 * F + 2 * F + t] + accV2 + sh_part[3][t];
        v[a * 3 * F + t] = vm0;
        v[a * 3 * F + F + t] = vm1;
        v[a * 3 * F + 2 * F + t] = vm2;
        vmid_h[(size_t)(a * 3 + 0) * F + t] = (_Float16)vm0;
        vmid_h[(size_t)(a * 3 + 1) * F + t] = (_Float16)vm1;
        vmid_h[(size_t)(a * 3 + 2) * F + t] = (_Float16)vm2;
    }
}

// ---------------------------------------------------------------- fused update, TA=16, 512 threads (8 waves)
__global__ __launch_bounds__(512) void fused_update_kernel(
    const _Float16* __restrict__ vmid_h, const _Float16* __restrict__ uvT,
    const _Float16* __restrict__ w1T, const float* __restrict__ b1,
    const _Float16* __restrict__ w2T, const float* __restrict__ b2,
    float* __restrict__ s, float* __restrict__ v, _Float16* __restrict__ pv,
    const _Float16* __restrict__ nw1T, const float* __restrict__ nb1,
    const _Float16* __restrict__ nw2T, const float* __restrict__ nb2,
    int do_phi,
    const _Float16* __restrict__ roT16, const float* __restrict__ rb1,
    const float* __restrict__ rw2, const float* __restrict__ rb2,
    float* __restrict__ out, int do_ro) {
    __shared__ __align__(16) _Float16 shA[48 * 136];    // vmid tile; reused as s-tile
    __shared__ __align__(16) _Float16 shUV[48 * 264];
    __shared__ __align__(16) _Float16 shCat[16 * 264];
    __shared__ __align__(16) _Float16 shH[16 * 136];
    __shared__ __align__(16) _Float16 shAa[16 * 392];
    _Float16* shS = shA;
    float* shRO = (float*)shAa;   // 16 x 68 f32 (alias, used only in do_ro after barrier)
    int a0 = blockIdx.x * 16;
    int r0 = a0 * 3;
    int tid = threadIdx.x;
    for (int slot = tid; slot < 48 * 16; slot += 512) {
        int r = slot >> 4, c8 = (slot & 15) * 8;
        int rg = r0 + r; if (rg >= N_ATOMS * 3) rg = N_ATOMS * 3 - 1;
        *(f16x8*)(shA + r * 136 + c8) = *(const f16x8*)(vmid_h + (size_t)rg * F + c8);
    }
    __syncthreads();
    int lane = tid & 63, wv = tid >> 6;   // wv in [0,8)
    int col = lane & 15, quad = lane >> 4;

    // stage 1: UV = vmid @ [U|V]
    for (int j = wv; j < 48; j += 8) {
        int mt = j >> 4, nt = j & 15;
        int n = nt * 16 + col;
        f32x4 acc = {0.f, 0.f, 0.f, 0.f};
#pragma unroll
        for (int kt = 0; kt < 4; ++kt) {
            f16x8 afr = *(const f16x8*)(shA + (mt * 16 + col) * 136 + kt * 32 + quad * 8);
            f16x8 bfr = *(const f16x8*)(uvT + (size_t)n * 128 + kt * 32 + quad * 8);
            acc = __builtin_amdgcn_mfma_f32_16x16x32_f16(afr, bfr, acc, 0, 0, 0);
        }
#pragma unroll
        for (int r = 0; r < 4; ++r)
            shUV[(mt * 16 + quad * 4 + r) * 264 + n] = (_Float16)acc[r];
    }
    __syncthreads();

    // stage 2: concat = [s, Vn]
    for (int p = tid; p < 2048; p += 512) {
        int ai = p >> 7, t = p & 127;
        int atom = a0 + ai;
        int ag = (atom < N_ATOMS) ? atom : N_ATOMS - 1;
        shCat[ai * 264 + t] = (_Float16)s[(size_t)ag * F + t];
        float x0 = (float)shUV[(ai * 3 + 0) * 264 + 128 + t];
        float x1 = (float)shUV[(ai * 3 + 1) * 264 + 128 + t];
        float x2 = (float)shUV[(ai * 3 + 2) * 264 + 128 + t];
        shCat[ai * 264 + 128 + t] = (_Float16)sqrtf(x0 * x0 + x1 * x1 + x2 * x2);
    }
    __syncthreads();

    // stage 3: hidden = silu(concat @ w1 + b1), K=256
    for (int nt = wv; nt < 8; nt += 8) {
        int n = nt * 16 + col;
        f32x4 acc = {0.f, 0.f, 0.f, 0.f};
#pragma unroll
        for (int kt = 0; kt < 8; ++kt) {
            f16x8 afr = *(const f16x8*)(shCat + col * 264 + kt * 32 + quad * 8);
            f16x8 bfr = *(const f16x8*)(w1T + (size_t)n * 256 + kt * 32 + quad * 8);
            acc = __builtin_amdgcn_mfma_f32_16x16x32_f16(afr, bfr, acc, 0, 0, 0);
        }
        float bb = b1[n];
#pragma unroll
        for (int r = 0; r < 4; ++r)
            shH[(quad * 4 + r) * 136 + n] = (_Float16)silu_f(acc[r] + bb);
    }
    __syncthreads();

    // stage 4: a = hidden @ w2 + b2
    for (int nt = wv; nt < 24; nt += 8) {
        int n = nt * 16 + col;
        f32x4 acc = {0.f, 0.f, 0.f, 0.f};
#pragma unroll
        for (int kt = 0; kt < 4; ++kt) {
            f16x8 afr = *(const f16x8*)(shH + col * 136 + kt * 32 + quad * 8);
            f16x8 bfr = *(const f16x8*)(w2T + (size_t)n * 128 + kt * 32 + quad * 8);
            acc = __builtin_amdgcn_mfma_f32_16x16x32_f16(afr, bfr, acc, 0, 0, 0);
        }
        float bb = b2[n];
#pragma unroll
        for (int r = 0; r < 4; ++r)
            shAa[(quad * 4 + r) * 392 + n] = (_Float16)(acc[r] + bb);
    }
    __syncthreads();

    // stage 5: final elementwise update; new s into shS (f16), new v into pv[3..5]
    for (int p = tid; p < 2048; p += 512) {
        int ai = p >> 7, t = p & 127;
        int atom = a0 + ai;
        if (atom >= N_ATOMS) { shS[ai * 136 + t] = (_Float16)0.0f; continue; }
        float avv = (float)shAa[ai * 392 + t];
        float asv = (float)shAa[ai * 392 + 128 + t];
        float ass = (float)shAa[ai * 392 + 256 + t];
        float dot = 0.f;
        _Float16* pvp = pv + PV_IDX(atom, t);
#pragma unroll
        for (int d = 0; d < 3; ++d) {
            float u = (float)shUV[(ai * 3 + d) * 264 + t];
            float w = (float)shUV[(ai * 3 + d) * 264 + 128 + t];
            dot += u * w;
            float nv = v[(size_t)atom * 3 * F + d * F + t] + avv * u;
            v[(size_t)atom * 3 * F + d * F + t] = nv;
            pvp[3 + d] = (_Float16)nv;
        }
        float sn = s[(size_t)atom * F + t] + asv * dot + ass;
        s[(size_t)atom * F + t] = sn;
        shS[ai * 136 + t] = (_Float16)sn;
    }

    // stage 6a: next layer's phi -> pv[0..2]
    if (do_phi) {
        __syncthreads();
        for (int nt = wv; nt < 8; nt += 8) {
            int n = nt * 16 + col;
            f32x4 acc = {0.f, 0.f, 0.f, 0.f};
#pragma unroll
            for (int kt = 0; kt < 4; ++kt) {
                f16x8 afr = *(const f16x8*)(shS + col * 136 + kt * 32 + quad * 8);
                f16x8 bfr = *(const f16x8*)(nw1T + (size_t)n * 128 + kt * 32 + quad * 8);
                acc = __builtin_amdgcn_mfma_f32_16x16x32_f16(afr, bfr, acc, 0, 0, 0);
            }
            float bb = nb1[n];
#pragma unroll
            for (int r = 0; r < 4; ++r)
                shH[(quad * 4 + r) * 136 + n] = (_Float16)silu_f(acc[r] + bb);
        }
        __syncthreads();
        for (int nt = wv; nt < 24; nt += 8) {
            int n = nt * 16 + col;
            f32x4 acc = {0.f, 0.f, 0.f, 0.f};
#pragma unroll
            for (int kt = 0; kt < 4; ++kt) {
                f16x8 afr = *(const f16x8*)(shH + col * 136 + kt * 32 + quad * 8);
                f16x8 bfr = *(const f16x8*)(nw2T + (size_t)n * 128 + kt * 32 + quad * 8);
                acc = __builtin_amdgcn_mfma_f32_16x16x32_f16(afr, bfr, acc, 0, 0, 0);
            }
            float bb = nb2[n];
#pragma unroll
            for (int r = 0; r < 4; ++r) {
                int row = a0 + quad * 4 + r;
                if (row < N_ATOMS)
                    pv[PV_IDX(row, n & 127) + (n >> 7)] = (_Float16)(acc[r] + bb);
            }
        }
    }

    // stage 6b: readout (last layer)
    if (do_ro) {
        __syncthreads();
        if (wv < 4) {
            int n = wv * 16 + col;   // n in [0,64)
            f32x4 acc = {0.f, 0.f, 0.f, 0.f};
#pragma unroll
            for (int kt = 0; kt < 4; ++kt) {
                f16x8 afr = *(const f16x8*)(shS + col * 136 + kt * 32 + quad * 8);
                f16x8 bfr = *(const f16x8*)(roT16 + (size_t)n * 128 + kt * 32 + quad * 8);
                acc = __builtin_amdgcn_mfma_f32_16x16x32_f16(afr, bfr, acc, 0, 0, 0);
            }
            float bb = rb1[n], w2n = rw2[n];
#pragma unroll
            for (int r = 0; r < 4; ++r)
                shRO[(quad * 4 + r) * 68 + n] = silu_f(acc[r] + bb) * w2n;
        }
        __syncthreads();
        if (tid < 16) {
            int atom = a0 + tid;
            if (atom < N_ATOMS) {
                float sum = rb2[0];
#pragma unroll 8
                for (int k = 0; k < 64; ++k) sum += shRO[tid * 68 + k];
                out[atom] = sum;
            }
        }
    }
}

extern "C" void kernel_launch(void* const* d_in, const int* in_sizes, int n_in,
                              void* d_out, int out_size, void* d_ws, size_t ws_size,
                              hipStream_t stream) {
    const int*   Z      = (const int*)d_in[0];
    const int*   eidx   = (const int*)d_in[1];
    const float* ediff  = (const float*)d_in[2];
    const float* edist  = (const float*)d_in[3];
    const float* emb    = (const float*)d_in[4];
    const float* msg_w1 = (const float*)d_in[5];
    const float* msg_b1 = (const float*)d_in[6];
    const float* msg_w2 = (const float*)d_in[7];
    const float* msg_b2 = (const float*)d_in[8];
    const float* filt_w = (const float*)d_in[9];
    const float* filt_b = (const float*)d_in[10];
    const float* upd_U  = (const float*)d_in[11];
    const float* upd_V  = (const float*)d_in[12];
    const float* upd_w1 = (const float*)d_in[13];
    const float* upd_b1 = (const float*)d_in[14];
    const float* upd_w2 = (const float*)d_in[15];
    const float* upd_b2 = (const float*)d_in[16];
    const float* ro_w1  = (const float*)d_in[17];
    const float* ro_b1  = (const float*)d_in[18];
    const float* ro_w2  = (const float*)d_in[19];
    const float* ro_b2  = (const float*)d_in[20];
    float* out = (float*)d_out;

    // ---------------- workspace layout ----------------
    float* ws = (float*)d_ws;
    float* s   = ws;                      // N*F f32
    float* v   = s + N_ATOMS * F;         // N*3F f32
    int* count  = (int*)(v + N_ATOMS * 3 * F);   // N
    int* bucket = count + N_ATOMS;               // N*CAP
    EMeta* meta = (EMeta*)(bucket + N_ATOMS * CAP);           // N*CAP*32B
    _Float16* rbfh = (_Float16*)(meta + N_ATOMS * CAP);       // N*CAP*24
    _Float16* s_h    = rbfh + (size_t)N_ATOMS * CAP * 24;     // N*F
    _Float16* vmid_h = s_h + (size_t)N_ATOMS * F;             // N*3F
    _Float16* pv     = vmid_h + (size_t)N_ATOMS * 3 * F;      // N*F*6
    _Float16* wh     = pv + (size_t)N_ATOMS * F * 6;          // f16 weights

    const int HWL = 16384 + 49152 + 32768 + 32768 + 49152 + 384 * 24;
    _Float16* mw1T = wh;                   // [128][128]
    _Float16* mw2T = wh + 16384;           // [384][128]
    _Float16* uvT  = wh + 65536;           // [256][128]
    _Float16* uw1T = wh + 98304;           // [128][256]
    _Float16* uw2T = wh + 131072;          // [384][128]
    _Float16* fwTl = wh + 180224;          // [384][24]
    _Float16* roT16 = wh + (size_t)NL * HWL;  // [64][128]

    // ---------------- transpose plan ----------------
    TPlansX P; int nb = 0, pi = 0;
    auto add = [&](const float* src, void* dst, int R, int C, int isf16, int pad) {
        P.p[pi].src = src; P.p[pi].dst = dst; P.p[pi].R = R; P.p[pi].C = C;
        P.p[pi].blk0 = nb; P.p[pi].isf16 = isf16; P.p[pi].pad = pad;
        nb += (R * C + 255) / 256; ++pi;
    };
    for (int l = 0; l < NL; ++l) {
        add(msg_w1 + l * F * F,     mw1T + (size_t)l * HWL, F, F, 1, F);
        add(msg_w2 + l * F * 3 * F, mw2T + (size_t)l * HWL, F, 3 * F, 1, F);
        add(upd_U  + l * F * F,     uvT  + (size_t)l * HWL, F, F, 1, F);
        add(upd_V  + l * F * F,     uvT  + (size_t)l * HWL + F * F, F, F, 1, F);
        add(upd_w1 + l * 2 * F * F, uw1T + (size_t)l * HWL, 2 * F, F, 1, 2 * F);
        add(upd_w2 + l * F * 3 * F, uw2T + (size_t)l * HWL, F, 3 * F, 1, F);
        add(filt_w + l * B * 3 * F, fwTl + (size_t)l * HWL, B, 3 * F, 1, 24);
    }
    add(ro_w1, roT16, F, 64, 1, F);
    P.n = pi;

    // ---------------- launch ----------------
    init_kernel<<<N_ATOMS, F, 0, stream>>>(Z, emb, s, s_h, v, pv, count);
    fill_buckets<<<(N_EDGES + 255) / 256, 256, 0, stream>>>(eidx, count, bucket);
    transpose_x<<<nb, 256, 0, stream>>>(P);
    edge_meta_kernel<<<(N_ATOMS * CAP + 255) / 256, 256, 0, stream>>>(
        count, bucket, eidx, ediff, edist, meta, rbfh);

    const int GB16 = (N_ATOMS + 15) / 16;   // 313
    phi_mlp_kernel<<<GB16, 256, 0, stream>>>(
        s_h, mw1T, msg_b1, mw2T, msg_b2, pv);
    for (int l = 0; l < NL; ++l) {
        edge_agg_kernel<<<N_ATOMS, 256, 0, stream>>>(
            count, meta, rbfh, fwTl + (size_t)l * HWL, filt_b + l * 3 * F,
            pv, s, v, vmid_h);
        int do_phi = (l + 1 < NL);
        int do_ro = (l == NL - 1);
        int ln = do_phi ? (l + 1) : l;
        fused_update_kernel<<<GB16, 512, 0, stream>>>(
            vmid_h, uvT + (size_t)l * HWL,
            uw1T + (size_t)l * HWL, upd_b1 + l * F,
            uw2T + (size_t)l * HWL, upd_b2 + l * 3 * F,
            s, v, pv,
            mw1T + (size_t)ln * HWL, msg_b1 + ln * F,
            mw2T + (size_t)ln * HWL, msg_b2 + ln * 3 * F, do_phi,
            roT16, ro_b1, ro_w2, ro_b2, out, do_ro);
    }
}